// Round 7
// baseline (81.803 us; speedup 1.0000x reference)
//
#include <hip/hip_runtime.h>
#include <math.h>

#define NN 8192
#define HH 128
#define LRELU_ALPHA 0.2f
#define R_ROWS 152          // rows with t_i possibly nonzero in f32 (i >= 8043), padded
#define I0 (NN - R_ROWS)    // 8040

// ---------- K1: u = W@a (fast redundant per block) + f1/f2 for 16 rows --------
//              block 0 additionally zeroes w[] and the completion counter
__global__ __launch_bounds__(256) void k_front(const float* __restrict__ inp,
                                               const float* __restrict__ W,
                                               const float* __restrict__ a,
                                               float* __restrict__ f1,
                                               float* __restrict__ f2,
                                               float* __restrict__ w,
                                               unsigned* __restrict__ counter) {
    __shared__ float u1s[HH], u2s[HH];
    const int tid = threadIdx.x, wave = tid >> 6, lane = tid & 63;

    if (blockIdx.x == 0) {
        float4 z4 = {0.f, 0.f, 0.f, 0.f};
        #pragma unroll
        for (int q = 0; q < 8; q++)
            ((float4*)w)[q * 256 + tid] = z4;
        if (tid == 0) *counter = 0u;
    }

    // u-compute: 2 threads per k (k = tid>>1), each half-row dot of length 64
    {
        int k = tid >> 1, half = tid & 1;
        const float4* wrow = (const float4*)(W + (size_t)k * HH + half * 64);
        const float4* a1v  = (const float4*)(a + half * 64);
        const float4* a2v  = (const float4*)(a + HH + half * 64);
        float p1 = 0.f, p2 = 0.f;
        #pragma unroll
        for (int q = 0; q < 16; q++) {
            float4 wv = wrow[q], b1 = a1v[q], b2 = a2v[q];
            p1 += wv.x * b1.x + wv.y * b1.y + wv.z * b1.z + wv.w * b1.w;
            p2 += wv.x * b2.x + wv.y * b2.y + wv.z * b2.z + wv.w * b2.w;
        }
        p1 += __shfl_xor(p1, 1);
        p2 += __shfl_xor(p2, 1);
        if (half == 0) { u1s[k] = p1; u2s[k] = p2; }
    }
    __syncthreads();

    // f-compute: 16 rows per block, 4 rows per wave
    float2 uv1 = ((const float2*)u1s)[lane];
    float2 uv2 = ((const float2*)u2s)[lane];
    int r0 = blockIdx.x * 16;
    for (int rr = wave; rr < 16; rr += 4) {
        int r = r0 + rr;
        float2 x = ((const float2*)(inp + (size_t)r * HH))[lane];
        float p1 = x.x * uv1.x + x.y * uv1.y;
        float p2 = x.x * uv2.x + x.y * uv2.y;
        for (int off = 32; off; off >>= 1) {
            p1 += __shfl_down(p1, off);
            p2 += __shfl_down(p2, off);
        }
        if (lane == 0) { f1[r] = p1; f2[r] = p2; }
    }
}

// ---------- K2: one A pass per row: Z_i, then atomicAdd w_j contributions ----
__global__ __launch_bounds__(512) void k_rowz(const int* __restrict__ A,
                                              const float* __restrict__ f1,
                                              const float* __restrict__ f2,
                                              float* __restrict__ w) {
    const int ii = blockIdx.x;
    const int i  = I0 + ii;
    const int tid = threadIdx.x, wave = tid >> 6, lane = tid & 63;
    __shared__ float red[8];

    const int4*   arow = (const int4*)(A + (size_t)i * NN);
    const float4* f2v  = (const float4*)f2;
    const float f1i = f1[i];

    float e[16];
    float z = 0.f;
    #pragma unroll
    for (int it = 0; it < 4; ++it) {
        int t = it * 512 + tid;
        int4   av = arow[t];
        float4 fv = f2v[t];
        int j0 = 4 * t;
        float x, val;
        x = f1i + fv.x; x = x > 0.f ? x : LRELU_ALPHA * x;
        val = ((av.x > 0) || (j0 + 0 == i)) ? __expf(x) : 0.f;
        e[4*it+0] = val; z += val;
        x = f1i + fv.y; x = x > 0.f ? x : LRELU_ALPHA * x;
        val = ((av.y > 0) || (j0 + 1 == i)) ? __expf(x) : 0.f;
        e[4*it+1] = val; z += val;
        x = f1i + fv.z; x = x > 0.f ? x : LRELU_ALPHA * x;
        val = ((av.z > 0) || (j0 + 2 == i)) ? __expf(x) : 0.f;
        e[4*it+2] = val; z += val;
        x = f1i + fv.w; x = x > 0.f ? x : LRELU_ALPHA * x;
        val = ((av.w > 0) || (j0 + 3 == i)) ? __expf(x) : 0.f;
        e[4*it+3] = val; z += val;
    }
    for (int off = 32; off; off >>= 1) z += __shfl_xor(z, off);
    if (lane == 0) red[wave] = z;
    __syncthreads();
    float zz = red[0];
    #pragma unroll
    for (int wv = 1; wv < 8; wv++) zz += red[wv];

    const float cz = exp2f((float)(i - NN)) / zz;   // normalized t_i / Z'_i
    #pragma unroll
    for (int it = 0; it < 4; ++it) {
        int j0 = 4 * (it * 512 + tid);
        #pragma unroll
        for (int c = 0; c < 4; c++) {
            float ev = e[4*it+c];
            if (ev != 0.f) atomicAdd(&w[j0 + c], cz * ev);
        }
    }
}

// ---------- K3: vpart = weighted inp sum per 64-j slice; last block: v@W+ELU --
__global__ __launch_bounds__(256) void k_tail(const float* __restrict__ inp,
                                              const float* __restrict__ W,
                                              const float* __restrict__ w,
                                              float* __restrict__ vpart,
                                              unsigned* __restrict__ counter,
                                              float* __restrict__ out) {
    const int b = blockIdx.x, jbase = b * 64, tid = threadIdx.x;
    __shared__ float red[256];
    __shared__ float wj[64];
    __shared__ float vfin[128];
    __shared__ unsigned sOld;

    if (tid < 64) wj[tid] = w[jbase + tid];
    __syncthreads();

    int k = tid & 127, half = tid >> 7;
    float v = 0.f;
    for (int j2 = half; j2 < 64; j2 += 2)
        v += wj[j2] * inp[(size_t)(jbase + j2) * HH + k];
    red[tid] = v;
    __syncthreads();
    if (half == 0) vpart[(size_t)b * HH + k] = red[k] + red[128 + k];

    // completion: last block does the final reduction + v@W + ELU
    __threadfence();
    if (tid == 0) sOld = atomicAdd(counter, 1u);
    __syncthreads();
    if (sOld == 127u) {
        __threadfence();
        float accv = 0.f;
        for (int bb = half; bb < 128; bb += 2)
            accv += vpart[(size_t)bb * HH + k];
        red[tid] = accv;
        __syncthreads();
        if (tid < 128) vfin[tid] = red[tid] + red[128 + tid];
        __syncthreads();
        float h = 0.f;
        for (int kk = half; kk < 128; kk += 2)
            h += vfin[kk] * W[(size_t)kk * HH + k];
        red[tid] = h;
        __syncthreads();
        if (tid < 128) {
            float ht = red[tid] + red[128 + tid];
            out[tid] = ht > 0.f ? ht : expm1f(ht);
        }
    }
}

extern "C" void kernel_launch(void* const* d_in, const int* in_sizes, int n_in,
                              void* d_out, int out_size, void* d_ws, size_t ws_size,
                              hipStream_t stream) {
    const float* inp = (const float*)d_in[0];   // [8192,128] f32
    const int*   A   = (const int*)d_in[1];     // [8192,8192] i32
    const float* W   = (const float*)d_in[2];   // [128,128] f32
    const float* a   = (const float*)d_in[3];   // [256,1] f32
    float* out = (float*)d_out;                 // [128] f32
    float* ws  = (float*)d_ws;

    // workspace layout (floats)
    float*    f1      = ws;                     // 8192
    float*    f2      = ws + NN;                // 8192
    float*    w       = ws + 2 * NN;            // 8192
    float*    vpart   = ws + 3 * NN;            // 128*128 = 16384
    unsigned* counter = (unsigned*)(vpart + 128 * HH);

    k_front<<<NN / 16, 256, 0, stream>>>(inp, W, a, f1, f2, w, counter);
    k_rowz <<<R_ROWS,  512, 0, stream>>>(A, f1, f2, w);
    k_tail <<<128,     256, 0, stream>>>(inp, W, w, vpart, counter, out);
}

// Round 8
// 74.420 us; speedup vs baseline: 1.0992x; 1.0992x over previous
//
#include <hip/hip_runtime.h>
#include <math.h>

#define NN 8192
#define HH 128
#define LRELU_ALPHA 0.2f
#define R_ROWS 152          // rows with t_i possibly nonzero in f32 (i >= 8043), padded
#define I0 (NN - R_ROWS)    // 8040
#define ZBLK R_ROWS         // producer blocks in k_mega
#define VBLK 128            // consumer blocks in k_mega

// ---------- K1: u = W@a (fast redundant per block) + f1/f2 for 16 rows --------
//              block 0 additionally zeroes the two completion counters
__global__ __launch_bounds__(256) void k_front(const float* __restrict__ inp,
                                               const float* __restrict__ W,
                                               const float* __restrict__ a,
                                               float* __restrict__ f1,
                                               float* __restrict__ f2,
                                               unsigned* __restrict__ counters) {
    __shared__ float u1s[HH], u2s[HH];
    const int tid = threadIdx.x, wave = tid >> 6, lane = tid & 63;

    if (blockIdx.x == 0 && tid < 2) counters[tid] = 0u;

    // u-compute: 2 threads per k (k = tid>>1), each half-row dot of length 64
    {
        int k = tid >> 1, half = tid & 1;
        const float4* wrow = (const float4*)(W + (size_t)k * HH + half * 64);
        const float4* a1v  = (const float4*)(a + half * 64);
        const float4* a2v  = (const float4*)(a + HH + half * 64);
        float p1 = 0.f, p2 = 0.f;
        #pragma unroll
        for (int q = 0; q < 16; q++) {
            float4 wv = wrow[q], b1 = a1v[q], b2 = a2v[q];
            p1 += wv.x * b1.x + wv.y * b1.y + wv.z * b1.z + wv.w * b1.w;
            p2 += wv.x * b2.x + wv.y * b2.y + wv.z * b2.z + wv.w * b2.w;
        }
        p1 += __shfl_xor(p1, 1);
        p2 += __shfl_xor(p2, 1);
        if (half == 0) { u1s[k] = p1; u2s[k] = p2; }
    }
    __syncthreads();

    // f-compute: 16 rows per block, 4 rows per wave
    float2 uv1 = ((const float2*)u1s)[lane];
    float2 uv2 = ((const float2*)u2s)[lane];
    int r0 = blockIdx.x * 16;
    for (int rr = wave; rr < 16; rr += 4) {
        int r = r0 + rr;
        float2 x = ((const float2*)(inp + (size_t)r * HH))[lane];
        float p1 = x.x * uv1.x + x.y * uv1.y;
        float p2 = x.x * uv2.x + x.y * uv2.y;
        for (int off = 32; off; off >>= 1) {
            p1 += __shfl_down(p1, off);
            p2 += __shfl_down(p2, off);
        }
        if (lane == 0) { f1[r] = p1; f2[r] = p2; }
    }
}

// ---------- K2 (mega): blocks 0..151 produce czrow; blocks 152..279 consume ---
__global__ __launch_bounds__(512) void k_mega(const int* __restrict__ A,
                                              const float* __restrict__ inp,
                                              const float* __restrict__ W,
                                              const float* __restrict__ f1,
                                              const float* __restrict__ f2,
                                              float* __restrict__ czrow,
                                              float* __restrict__ vpart,
                                              unsigned* __restrict__ counters,
                                              float* __restrict__ out) {
    const int tid = threadIdx.x, wave = tid >> 6, lane = tid & 63;

    if (blockIdx.x < ZBLK) {
        // ---------------- producer: czrow[ii] = t_i / Z'_i ----------------
        const int ii = blockIdx.x;
        const int i  = I0 + ii;
        __shared__ float red[8];
        const int4*   arow = (const int4*)(A + (size_t)i * NN);
        const float4* f2v  = (const float4*)f2;
        const float f1i = f1[i];

        float z = 0.f;
        #pragma unroll
        for (int it = 0; it < 4; ++it) {
            int t = it * 512 + tid;
            int4   av = arow[t];
            float4 fv = f2v[t];
            int j0 = 4 * t;
            float x;
            x = f1i + fv.x; x = x > 0.f ? x : LRELU_ALPHA * x;
            z += ((av.x > 0) || (j0 + 0 == i)) ? __expf(x) : 0.f;
            x = f1i + fv.y; x = x > 0.f ? x : LRELU_ALPHA * x;
            z += ((av.y > 0) || (j0 + 1 == i)) ? __expf(x) : 0.f;
            x = f1i + fv.z; x = x > 0.f ? x : LRELU_ALPHA * x;
            z += ((av.z > 0) || (j0 + 2 == i)) ? __expf(x) : 0.f;
            x = f1i + fv.w; x = x > 0.f ? x : LRELU_ALPHA * x;
            z += ((av.w > 0) || (j0 + 3 == i)) ? __expf(x) : 0.f;
        }
        for (int off = 32; off; off >>= 1) z += __shfl_xor(z, off);
        if (lane == 0) red[wave] = z;
        __syncthreads();
        if (tid == 0) {
            float zz = red[0];
            #pragma unroll
            for (int w = 1; w < 8; w++) zz += red[w];
            czrow[ii] = exp2f((float)(i - NN)) / zz;
            __threadfence();                 // publish czrow[ii]
            atomicAdd(&counters[0], 1u);     // release
        }
        return;
    }

    // ---------------- consumer: w_j, vpart, (last block) final ----------------
    const int b = blockIdx.x - ZBLK;       // 0..127
    const int jbase = b * 64;
    __shared__ float red[512];
    __shared__ float wj[64];
    __shared__ float f1s[R_ROWS], czs[R_ROWS];
    __shared__ float vfin[128];
    __shared__ unsigned sOld;

    if (tid < R_ROWS) f1s[tid] = f1[I0 + tid];
    __syncthreads();

    // prefetch masked exps into registers BEFORE the gate (overlaps producers)
    const int jj = tid & 63, ic = tid >> 6;    // 8 i-groups x 64 j-lanes
    const int j = jbase + jj;
    const float f2j = f2[j];
    float e_reg[19];                            // 152 = 8 * 19
    #pragma unroll
    for (int q = 0; q < 19; q++) {
        int ii = ic + q * 8;
        int av = A[(size_t)(I0 + ii) * NN + j];
        float x = f1s[ii] + f2j;
        x = x > 0.f ? x : LRELU_ALPHA * x;
        float e = __expf(x);
        e_reg[q] = ((av > 0) || (j == I0 + ii)) ? e : 0.f;
    }

    // gate: wait for all 152 producers
    if (tid == 0) {
        while (__hip_atomic_load(&counters[0], __ATOMIC_ACQUIRE,
                                 __HIP_MEMORY_SCOPE_AGENT) < (unsigned)ZBLK)
            __builtin_amdgcn_s_sleep(2);
    }
    __syncthreads();
    __threadfence();
    if (tid < R_ROWS) czs[tid] = czrow[tid];
    __syncthreads();

    float w = 0.f;
    #pragma unroll
    for (int q = 0; q < 19; q++) w += czs[ic + q * 8] * e_reg[q];
    red[ic * 64 + jj] = w;
    __syncthreads();
    if (tid < 64) {
        float s = 0.f;
        #pragma unroll
        for (int g = 0; g < 8; g++) s += red[g * 64 + tid];
        wj[tid] = s;
    }
    __syncthreads();

    // weighted sum of inp rows for this j-range
    const int k = tid & 127, qq = tid >> 7;
    float v = 0.f;
    for (int j2 = qq; j2 < 64; j2 += 4)
        v += wj[j2] * inp[(size_t)(jbase + j2) * HH + k];
    red[tid] = v;
    __syncthreads();
    if (tid < 128)
        vpart[(size_t)b * HH + tid] =
            red[tid] + red[128 + tid] + red[256 + tid] + red[384 + tid];

    // completion: last consumer block does v-sum + v@W + ELU
    __threadfence();
    if (tid == 0) sOld = atomicAdd(&counters[1], 1u);
    __syncthreads();
    if (sOld == VBLK - 1) {
        __threadfence();
        float accv = 0.f;
        for (int bb = qq; bb < VBLK; bb += 4)
            accv += vpart[(size_t)bb * HH + k];
        red[qq * 128 + k] = accv;
        __syncthreads();
        if (tid < 128)
            vfin[tid] = red[tid] + red[128 + tid] + red[256 + tid] + red[384 + tid];
        __syncthreads();
        float h = 0.f;
        for (int kk = qq; kk < 128; kk += 4)
            h += vfin[kk] * W[(size_t)kk * HH + k];
        red[qq * 128 + k] = h;
        __syncthreads();
        if (tid < 128) {
            float ht = red[tid] + red[128 + tid] + red[256 + tid] + red[384 + tid];
            out[tid] = ht > 0.f ? ht : expm1f(ht);
        }
    }
}

extern "C" void kernel_launch(void* const* d_in, const int* in_sizes, int n_in,
                              void* d_out, int out_size, void* d_ws, size_t ws_size,
                              hipStream_t stream) {
    const float* inp = (const float*)d_in[0];   // [8192,128] f32
    const int*   A   = (const int*)d_in[1];     // [8192,8192] i32
    const float* W   = (const float*)d_in[2];   // [128,128] f32
    const float* a   = (const float*)d_in[3];   // [256,1] f32
    float* out = (float*)d_out;                 // [128] f32
    float* ws  = (float*)d_ws;

    // workspace layout (floats)
    float*    f1       = ws;                    // 8192
    float*    f2       = ws + NN;               // 8192
    float*    czrow    = ws + 2 * NN;           // 160 (152 used)
    float*    vpart    = czrow + 160;           // 128*128
    unsigned* counters = (unsigned*)(vpart + VBLK * HH);  // [2]

    k_front<<<NN / 16,    256, 0, stream>>>(inp, W, a, f1, f2, counters);
    k_mega <<<ZBLK + VBLK, 512, 0, stream>>>(A, inp, W, f1, f2, czrow, vpart,
                                             counters, out);
}

// Round 9
// 37.174 us; speedup vs baseline: 2.2005x; 2.0019x over previous
//
#include <hip/hip_runtime.h>
#include <math.h>

#define NN 8192
#define HH 128
#define LRELU_ALPHA 0.2f
#define R_ROWS 32           // rows with t_i >= 2^-32; truncation error < 2e-9
#define I0 (NN - R_ROWS)    // 8160

// ---------- K1: u = W@a (fast redundant per block) + f1/f2 for 16 rows --------
__global__ __launch_bounds__(256) void k_front(const float* __restrict__ inp,
                                               const float* __restrict__ W,
                                               const float* __restrict__ a,
                                               float* __restrict__ f1,
                                               float* __restrict__ f2) {
    __shared__ float u1s[HH], u2s[HH];
    const int tid = threadIdx.x, wave = tid >> 6, lane = tid & 63;

    // u-compute: 2 threads per k (k = tid>>1), each half-row dot of length 64
    {
        int k = tid >> 1, half = tid & 1;
        const float4* wrow = (const float4*)(W + (size_t)k * HH + half * 64);
        const float4* a1v  = (const float4*)(a + half * 64);
        const float4* a2v  = (const float4*)(a + HH + half * 64);
        float p1 = 0.f, p2 = 0.f;
        #pragma unroll
        for (int q = 0; q < 16; q++) {
            float4 wv = wrow[q], b1 = a1v[q], b2 = a2v[q];
            p1 += wv.x * b1.x + wv.y * b1.y + wv.z * b1.z + wv.w * b1.w;
            p2 += wv.x * b2.x + wv.y * b2.y + wv.z * b2.z + wv.w * b2.w;
        }
        p1 += __shfl_xor(p1, 1);
        p2 += __shfl_xor(p2, 1);
        if (half == 0) { u1s[k] = p1; u2s[k] = p2; }
    }
    __syncthreads();

    // f-compute: 16 rows per block, 4 rows per wave
    float2 uv1 = ((const float2*)u1s)[lane];
    float2 uv2 = ((const float2*)u2s)[lane];
    int r0 = blockIdx.x * 16;
    for (int rr = wave; rr < 16; rr += 4) {
        int r = r0 + rr;
        float2 x = ((const float2*)(inp + (size_t)r * HH))[lane];
        float p1 = x.x * uv1.x + x.y * uv1.y;
        float p2 = x.x * uv2.x + x.y * uv2.y;
        for (int off = 32; off; off >>= 1) {
            p1 += __shfl_down(p1, off);
            p2 += __shfl_down(p2, off);
        }
        if (lane == 0) { f1[r] = p1; f2[r] = p2; }
    }
}

// ---------- K2: czrow[ii] = t_i / sum_validj exp(s_ij)  (no-max softmax) ------
__global__ __launch_bounds__(512) void k_zrow(const int* __restrict__ A,
                                              const float* __restrict__ f1,
                                              const float* __restrict__ f2,
                                              float* __restrict__ czrow) {
    const int ii = blockIdx.x;
    const int i  = I0 + ii;
    const int tid = threadIdx.x, wave = tid >> 6, lane = tid & 63;
    __shared__ float red[8];

    const int4*   arow = (const int4*)(A + (size_t)i * NN);
    const float4* f2v  = (const float4*)f2;
    const float f1i = f1[i];

    float z = 0.f;
    #pragma unroll
    for (int it = 0; it < 4; ++it) {
        int t = it * 512 + tid;
        int4   av = arow[t];
        float4 fv = f2v[t];
        int j0 = 4 * t;
        float x;
        x = f1i + fv.x; x = x > 0.f ? x : LRELU_ALPHA * x;
        z += ((av.x > 0) || (j0 + 0 == i)) ? __expf(x) : 0.f;
        x = f1i + fv.y; x = x > 0.f ? x : LRELU_ALPHA * x;
        z += ((av.y > 0) || (j0 + 1 == i)) ? __expf(x) : 0.f;
        x = f1i + fv.z; x = x > 0.f ? x : LRELU_ALPHA * x;
        z += ((av.z > 0) || (j0 + 2 == i)) ? __expf(x) : 0.f;
        x = f1i + fv.w; x = x > 0.f ? x : LRELU_ALPHA * x;
        z += ((av.w > 0) || (j0 + 3 == i)) ? __expf(x) : 0.f;
    }
    for (int off = 32; off; off >>= 1) z += __shfl_xor(z, off);
    if (lane == 0) red[wave] = z;
    __syncthreads();
    if (tid == 0) {
        float zz = red[0];
        #pragma unroll
        for (int w = 1; w < 8; w++) zz += red[w];
        czrow[ii] = exp2f((float)(i - NN)) / zz;   // normalized t_i / Z'_i
    }
}

// ---------- K3: w_j (64 j's/block), vpart, then hpart_b = vpart_b @ W ---------
__global__ __launch_bounds__(256) void k_wv(const int* __restrict__ A,
                                            const float* __restrict__ inp,
                                            const float* __restrict__ W,
                                            const float* __restrict__ f1,
                                            const float* __restrict__ f2,
                                            const float* __restrict__ czrow,
                                            float* __restrict__ hpart) {
    const int b = blockIdx.x;          // 128 blocks
    const int jbase = b * 64;
    const int tid = threadIdx.x;
    const int jj = tid & 63, ic = tid >> 6;   // 4 i-groups x 64 j-lanes
    __shared__ float red[256];
    __shared__ float wj[64];
    __shared__ float f1s[R_ROWS], czs[R_ROWS];
    __shared__ float vfin[128];

    if (tid < R_ROWS) {
        f1s[tid] = f1[I0 + tid];
        czs[tid] = czrow[tid];
    }
    __syncthreads();

    const int j = jbase + jj;
    const float f2j = f2[j];

    float w = 0.f;
    #pragma unroll
    for (int q = 0; q < R_ROWS / 4; q++) {    // 8 iterations
        int ii = q * 4 + ic;
        int av = A[(size_t)(I0 + ii) * NN + j];
        float x = f1s[ii] + f2j;
        x = x > 0.f ? x : LRELU_ALPHA * x;
        float e = __expf(x);
        w += ((av > 0) || (j == I0 + ii)) ? czs[ii] * e : 0.f;
    }
    red[ic * 64 + jj] = w;
    __syncthreads();
    if (tid < 64) wj[tid] = red[tid] + red[64 + tid] + red[128 + tid] + red[192 + tid];
    __syncthreads();

    // weighted sum of inp rows for this j-range -> vfin[128]
    int k = tid & 127, half = tid >> 7;
    float v = 0.f;
    for (int j2 = half; j2 < 64; j2 += 2)
        v += wj[j2] * inp[(size_t)(jbase + j2) * HH + k];
    red[tid] = v;
    __syncthreads();
    if (half == 0) vfin[k] = red[k] + red[128 + k];
    __syncthreads();

    // hpart_b[e] = sum_k vfin[k] * W[k][e]
    float h = 0.f;
    for (int kk = half; kk < HH; kk += 2)
        h += vfin[kk] * W[(size_t)kk * HH + k];
    red[tid] = h;
    __syncthreads();
    if (half == 0) hpart[(size_t)b * HH + k] = red[k] + red[128 + k];
}

// ---------- K4: h_t = sum_b hpart_b; out = elu(h_t) ----------
__global__ __launch_bounds__(256) void k_final(const float* __restrict__ hpart,
                                               float* __restrict__ out) {
    __shared__ float4 red4[256];
    const int tid = threadIdx.x;
    const int e4 = tid & 31, g = tid >> 5;    // 8 groups x 32 float4-slots
    const float4* hp4 = (const float4*)hpart;
    float4 acc = {0.f, 0.f, 0.f, 0.f};
    for (int b = g; b < 128; b += 8) {
        float4 x = hp4[(size_t)b * 32 + e4];
        acc.x += x.x; acc.y += x.y; acc.z += x.z; acc.w += x.w;
    }
    red4[g * 32 + e4] = acc;
    __syncthreads();
    if (tid < 32) {
        float4 h = red4[tid];
        #pragma unroll
        for (int gg = 1; gg < 8; gg++) {
            float4 x = red4[gg * 32 + tid];
            h.x += x.x; h.y += x.y; h.z += x.z; h.w += x.w;
        }
        h.x = h.x > 0.f ? h.x : expm1f(h.x);
        h.y = h.y > 0.f ? h.y : expm1f(h.y);
        h.z = h.z > 0.f ? h.z : expm1f(h.z);
        h.w = h.w > 0.f ? h.w : expm1f(h.w);
        ((float4*)out)[tid] = h;
    }
}

extern "C" void kernel_launch(void* const* d_in, const int* in_sizes, int n_in,
                              void* d_out, int out_size, void* d_ws, size_t ws_size,
                              hipStream_t stream) {
    const float* inp = (const float*)d_in[0];   // [8192,128] f32
    const int*   A   = (const int*)d_in[1];     // [8192,8192] i32
    const float* W   = (const float*)d_in[2];   // [128,128] f32
    const float* a   = (const float*)d_in[3];   // [256,1] f32
    float* out = (float*)d_out;                 // [128] f32
    float* ws  = (float*)d_ws;

    // workspace layout (floats)
    float* f1    = ws;               // 8192
    float* f2    = ws + NN;          // 8192
    float* czrow = ws + 2 * NN;      // 32 (padded 64)
    float* hpart = czrow + 64;       // 128*128

    k_front<<<NN / 16, 256, 0, stream>>>(inp, W, a, f1, f2);
    k_zrow <<<R_ROWS,  512, 0, stream>>>(A, f1, f2, czrow);
    k_wv   <<<128,     256, 0, stream>>>(A, inp, W, f1, f2, czrow, hpart);
    k_final<<<1,       256, 0, stream>>>(hpart, out);
}